// Round 11
// baseline (361.058 us; speedup 1.0000x reference)
//
#include <hip/hip_runtime.h>
#include <hip/hip_bf16.h>

// MHA forward on MI355X: B=4, S=2048, H=16, D=64, HIDDEN=1024. fp32 in/out.
// Stage 0: convert x, Wq, Wk, Wv, Wo to bf16 in workspace (one pass).
// Stage 1: QKV GEMM (global_load_lds staging, XOR-swizzled LDS).
//          Q -> TRANSPOSED [B,H,D,S], PRE-SCALED by log2(e)/sqrt(D);
//          K -> [B,H,S,D]; V -> TRANSPOSED [B,H,D,S].
// Stage 2: flash attention, 32x32x16 MFMA. R11: K fragments are read DIRECTLY
//          from global (L1/L2-resident; all 4 waves share the tile) instead of
//          through LDS -- R10 pipe audit showed LDS at ~55% busy (80 KB per
//          block-tile, 4x read amplification) while the vector-L1 path idled.
//          LDS now carries only V (dbuf, 16 KB).
// Stage 3: out = attn @ Wo^T + bo (fp32 out).

typedef __attribute__((ext_vector_type(8)))  short short8;    // 8 x bf16
typedef __attribute__((ext_vector_type(4)))  float floatx4;   // 16x16 C/D
typedef __attribute__((ext_vector_type(16))) float floatx16;  // 32x32 C/D

#define HID 1024
#define SEQ 2048
#define BATCH 4
#define NH 16
#define HD 64
#define M_TOT (BATCH * SEQ)   // 8192

#define BM 128
#define BN 128
#define BK 64

#define SCALE2 0.1803368801111204f   // (1/sqrt(64)) * log2(e)

typedef const __attribute__((address_space(1))) void g_void;
typedef __attribute__((address_space(3))) void lds_void;

static __device__ __forceinline__ ushort f2bf(float f) {
    union { float f; unsigned int u; } v;
    v.f = f;
    unsigned int u = v.u;
    return (ushort)((u + 0x7fffu + ((u >> 16) & 1u)) >> 16);  // RNE
}
static __device__ __forceinline__ ushort4 f4tobf(float4 f) {
    ushort4 r;
    r.x = f2bf(f.x); r.y = f2bf(f.y); r.z = f2bf(f.z); r.w = f2bf(f.w);
    return r;
}
static __device__ __forceinline__ unsigned int fbits(float f) {
    union { float f; unsigned int u; } v; v.f = f; return v.u;
}

// ---------------------------------------------------------------------------
// Stage 0: fp32 -> bf16 conversion for x and the four weight matrices.
// ---------------------------------------------------------------------------
#define X_F4 (M_TOT * HID / 4)   // 2,097,152 float4s
#define W_F4 (HID * HID / 4)     //   262,144 float4s

__global__ __launch_bounds__(256) void convert_bf16(
    const float* __restrict__ x,
    const float* __restrict__ wq, const float* __restrict__ wk,
    const float* __restrict__ wv, const float* __restrict__ wo,
    ushort* __restrict__ xo,
    ushort* __restrict__ wqo, ushort* __restrict__ wko,
    ushort* __restrict__ wvo, ushort* __restrict__ woo)
{
    long i = (long)blockIdx.x * 256 + threadIdx.x;
    const float4* src; ushort4* dst; long off;
    if (i < X_F4)                  { src = (const float4*)x;  dst = (ushort4*)xo;  off = i; }
    else if (i < X_F4 + W_F4)      { src = (const float4*)wq; dst = (ushort4*)wqo; off = i - X_F4; }
    else if (i < X_F4 + 2 * W_F4)  { src = (const float4*)wk; dst = (ushort4*)wko; off = i - X_F4 - W_F4; }
    else if (i < X_F4 + 3 * W_F4)  { src = (const float4*)wv; dst = (ushort4*)wvo; off = i - X_F4 - 2 * W_F4; }
    else                           { src = (const float4*)wo; dst = (ushort4*)woo; off = i - X_F4 - 3 * W_F4; }
    dst[off] = f4tobf(src[off]);
}

// ---------------------------------------------------------------------------
// bf16 NT GEMM, m97 structure (global_load_lds width-16, XOR chunk swizzle).
// MODE 1: z=0 -> Q^T [B,H,D,S] pre-scaled; z=1 -> K [B,H,S,D]; z=2 -> V^T.
// MODE 0: fp32 row-major output (of).
// ---------------------------------------------------------------------------
template <int MODE>
__global__ __launch_bounds__(256) void gemm_bf(
    const ushort* __restrict__ A,
    const ushort* __restrict__ W0, const ushort* __restrict__ W1,
    const ushort* __restrict__ W2,
    const float* __restrict__ b0, const float* __restrict__ b1,
    const float* __restrict__ b2,
    ushort* __restrict__ o0, ushort* __restrict__ o1, ushort* __restrict__ o2,
    float* __restrict__ of)
{
    __shared__ ushort As[BM * BK];   // 16 KB
    __shared__ ushort Bs[BN * BK];   // 16 KB

    const int tid  = threadIdx.x;
    const int wave = tid >> 6;
    const int lane = tid & 63;
    const int l16  = lane & 15;
    const int lq   = lane >> 4;

    const int m0 = blockIdx.x * BM;
    const int n0 = blockIdx.y * BN;
    const int z  = (MODE == 1) ? blockIdx.z : 0;

    const ushort* W   = (z == 0) ? W0 : (z == 1) ? W1 : W2;
    const float* bias = (z == 0) ? b0 : (z == 1) ? b1 : b2;

    const int wm = (wave & 1) * 64;
    const int wn = (wave >> 1) * 64;

    const int srow = lane >> 3;
    const int schk = (lane & 7) ^ srow;
    const ushort* gA = A + (size_t)(m0 + wave * 32 + srow) * HID + schk * 8;
    const ushort* gW = W + (size_t)(n0 + wave * 32 + srow) * HID + schk * 8;
    ushort* lA = As + (wave * 32) * BK;
    ushort* lB = Bs + (wave * 32) * BK;

    floatx4 acc[4][4];
#pragma unroll
    for (int i = 0; i < 4; i++)
#pragma unroll
        for (int j = 0; j < 4; j++)
            acc[i][j] = (floatx4){0.f, 0.f, 0.f, 0.f};

    for (int k0 = 0; k0 < HID; k0 += BK) {
        __syncthreads();
#pragma unroll
        for (int i = 0; i < 4; i++) {
            __builtin_amdgcn_global_load_lds(
                (g_void*)(gA + (size_t)(8 * i) * HID + k0),
                (lds_void*)(lA + (8 * i) * BK), 16, 0, 0);
            __builtin_amdgcn_global_load_lds(
                (g_void*)(gW + (size_t)(8 * i) * HID + k0),
                (lds_void*)(lB + (8 * i) * BK), 16, 0, 0);
        }
        __syncthreads();

        const int sw = l16 & 7;
#pragma unroll
        for (int kk8 = 0; kk8 < 8; kk8 += 4) {
            short8 a[4], b[4];
#pragma unroll
            for (int i = 0; i < 4; i++)
                a[i] = *(const short8*)(&As[(wm + i * 16 + l16) * BK + ((lq + kk8) ^ sw) * 8]);
#pragma unroll
            for (int j = 0; j < 4; j++)
                b[j] = *(const short8*)(&Bs[(wn + j * 16 + l16) * BK + ((lq + kk8) ^ sw) * 8]);
#pragma unroll
            for (int i = 0; i < 4; i++)
#pragma unroll
                for (int j = 0; j < 4; j++)
                    acc[i][j] = __builtin_amdgcn_mfma_f32_16x16x32_bf16(
                        a[i], b[j], acc[i][j], 0, 0, 0);
        }
    }

    if (MODE == 0) {
#pragma unroll
        for (int j = 0; j < 4; j++) {
            int n = n0 + wn + j * 16 + l16;
            float bv = bias[n];
#pragma unroll
            for (int i = 0; i < 4; i++)
#pragma unroll
                for (int r = 0; r < 4; r++) {
                    int m = m0 + wm + i * 16 + lq * 4 + r;
                    of[(size_t)m * HID + n] = acc[i][j][r] + bv;
                }
        }
    } else if (z == 1) {
        // K: [B,H,S,D] scatter
        ushort* out = o1;
#pragma unroll
        for (int j = 0; j < 4; j++) {
            int n = n0 + wn + j * 16 + l16;
            float bv = bias[n];
            int h_ = n >> 6, d_ = n & (HD - 1);
#pragma unroll
            for (int i = 0; i < 4; i++)
#pragma unroll
                for (int r = 0; r < 4; r++) {
                    int m = m0 + wm + i * 16 + lq * 4 + r;
                    int b_ = m >> 11, s_ = m & (SEQ - 1);
                    out[(((size_t)b_ * NH + h_) * SEQ + s_) * HD + d_] =
                        f2bf(acc[i][j][r] + bv);
                }
        }
    } else {
        // z==0 (Q^T, pre-scaled) / z==2 (V^T): [B,H,D,S], 8B vector stores
        ushort* out = (z == 0) ? o0 : o2;
        const float sc = (z == 0) ? SCALE2 : 1.0f;
#pragma unroll
        for (int j = 0; j < 4; j++) {
            int n = n0 + wn + j * 16 + l16;
            float bv = bias[n];
            int h_ = n >> 6, d_ = n & (HD - 1);
#pragma unroll
            for (int i = 0; i < 4; i++) {
                int m = m0 + wm + i * 16 + lq * 4;
                int b_ = m >> 11, s0 = m & (SEQ - 1);
                ushort4 pk;
                pk.x = f2bf((acc[i][j][0] + bv) * sc);
                pk.y = f2bf((acc[i][j][1] + bv) * sc);
                pk.z = f2bf((acc[i][j][2] + bv) * sc);
                pk.w = f2bf((acc[i][j][3] + bv) * sc);
                *(ushort4*)(out + (((size_t)b_ * NH + h_) * HD + d_) * SEQ + s0) = pk;
            }
        }
    }
}

// ---------------------------------------------------------------------------
// Stage 2: flash attention, 32x32x16 MFMA, fixed-base softmax.
// Block = 128 Q rows of one (b,h); wave owns 32 q (q = l32).
// K fragments read DIRECTLY from global ([B,H,S,D]; L1/L2-resident, shared by
// all 4 waves). V^T staged in LDS (dbuf, global_load_lds + XOR swizzle).
// QK: S^T = mfma32(A=K, B=Q); C/D col=q=lane&31, row=(reg&3)+8*(reg>>2)+4*hi.
// PV: O^T = mfma32(A=V^T, B=P^T); P B-frag built with one shfl_xor(32) pair
// + cndmasks per 16-s chunk.
// ---------------------------------------------------------------------------
__global__ __launch_bounds__(256, 4) void attn_flash(
    const ushort* __restrict__ q, const ushort* __restrict__ k,
    const ushort* __restrict__ v, ushort* __restrict__ o)
{
    __shared__ ushort Vs[2 * 64 * 64];  // 16 KB, [buf][d][s_local] swizzled

    const int tid  = threadIdx.x;
    const int wave = tid >> 6;
    const int lane = tid & 63;
    const int l32  = lane & 31;
    const int hi   = lane >> 5;
    const int e    = l32 & 7;

    const int qb = blockIdx.x;   // 0..15 (128-row Q tiles)
    const int bh = blockIdx.y;   // 0..63
    const int b_ = bh >> 4, h_ = bh & 15;

    const size_t base = (size_t)bh * SEQ * HD;
    const ushort* Qt = q + base;   // [d][s]
    const ushort* K  = k + base;   // [s][d]
    const ushort* Vt = v + base;   // [d][s]

    const int q0 = qb * 128 + wave * 32;

    // Q B-frags: B[n = q0+l32][k = d = dk*16 + hi*8 + jj], one-time scalar loads
    short8 qf[4];
#pragma unroll
    for (int dk = 0; dk < 4; dk++)
#pragma unroll
        for (int jj = 0; jj < 8; jj++)
            qf[dk][jj] = (short)Qt[(size_t)(dk * 16 + hi * 8 + jj) * SEQ + q0 + l32];

    // per-lane K fragment pointer: row (l32), d-chunk (dk*16 + hi*8)
    const ushort* gKf = K + (size_t)l32 * HD + hi * 8;

    const int srow = lane >> 3;
    const int schk = (lane & 7) ^ srow;
    const ushort* gV = Vt + (size_t)(wave * 8 + srow) * SEQ + schk * 8;

    floatx16 oacc[2];
#pragma unroll
    for (int dm = 0; dm < 2; dm++)
#pragma unroll
        for (int r = 0; r < 16; r++) oacc[dm][r] = 0.f;
    float l_ = 0.f;

    // prologue: stage V tile 0 into buffer 0
#pragma unroll
    for (int i = 0; i < 2; i++) {
        __builtin_amdgcn_global_load_lds(
            (g_void*)(gV + (size_t)(i * 32) * SEQ),
            (lds_void*)(Vs + (i * 32 + wave * 8) * 64), 16, 0, 0);
    }

    for (int t = 0; t < SEQ / 64; t++) {
        __syncthreads();   // V tile t staged; prior reads of the other buf done

        if (t + 1 < SEQ / 64) {
            const int nb = (t + 1) & 1;
#pragma unroll
            for (int i = 0; i < 2; i++) {
                __builtin_amdgcn_global_load_lds(
                    (g_void*)(gV + (size_t)(i * 32) * SEQ + (t + 1) * 64),
                    (lds_void*)(Vs + nb * 4096 + (i * 32 + wave * 8) * 64), 16, 0, 0);
            }
        }

        const ushort* Vb = Vs + (t & 1) * 4096;

        // S^T: 2 m-tiles of 32 s x 32 q; K fragments straight from global
        floatx16 st[2];
#pragma unroll
        for (int mt = 0; mt < 2; mt++) {
#pragma unroll
            for (int r = 0; r < 16; r++) st[mt][r] = 0.f;
#pragma unroll
            for (int dk = 0; dk < 4; dk++) {
                short8 kf = *(const short8*)(
                    gKf + (size_t)(t * 64 + mt * 32) * HD + dk * 16);
                st[mt] = __builtin_amdgcn_mfma_f32_32x32x16_bf16(
                    kf, qf[dk], st[mt], 0, 0, 0);
            }
        }

        // p = exp2(s) (raw v_exp_f32); pack bf16 pairs; accumulate l
        unsigned int P32[2][8];
        float rs = 0.f;
#pragma unroll
        for (int mt = 0; mt < 2; mt++) {
            float p[16];
#pragma unroll
            for (int r = 0; r < 16; r++) {
                p[r] = __builtin_amdgcn_exp2f(st[mt][r]);
                rs += p[r];
            }
#pragma unroll
            for (int rr = 0; rr < 8; rr++)
                P32[mt][rr] = __builtin_amdgcn_perm(
                    fbits(p[2 * rr + 1]), fbits(p[2 * rr]), 0x07060302u);
        }
        l_ += rs;

        // PV: per 16-s chunk sc, build P B-frag via lane^32 exchange.
#pragma unroll
        for (int sc = 0; sc < 4; sc++) {
            const int mt = sc >> 1;
            const int bse = 4 * (sc & 1);
            unsigned int X = P32[mt][bse],     Y = P32[mt][bse + 1];
            unsigned int Z = P32[mt][bse + 2], W = P32[mt][bse + 3];
            unsigned int sendA = hi ? X : Z;
            unsigned int sendB = hi ? Y : W;
            unsigned int recvA = (unsigned int)__shfl_xor((int)sendA, 32, 64);
            unsigned int recvB = (unsigned int)__shfl_xor((int)sendB, 32, 64);
            unsigned int u0 = hi ? recvA : X;
            unsigned int u1 = hi ? recvB : Y;
            unsigned int u2 = hi ? Z : recvA;
            unsigned int u3 = hi ? W : recvB;
            union { unsigned int u[4]; short8 s; } pfr;
            pfr.u[0] = u0; pfr.u[1] = u1; pfr.u[2] = u2; pfr.u[3] = u3;
#pragma unroll
            for (int dm = 0; dm < 2; dm++) {
                short8 vf = *(const short8*)(
                    &Vb[(dm * 32 + l32) * 64 + ((2 * sc + hi) ^ e) * 8]);
                oacc[dm] = __builtin_amdgcn_mfma_f32_32x32x16_bf16(
                    vf, pfr.s, oacc[dm], 0, 0, 0);
            }
        }
    }

    // each lane covers half the s-range; partner lane^32 has the other half
    l_ += __shfl_xor(l_, 32, 64);

    {
        const int qg = q0 + l32;
        const float invl = 1.0f / l_;
#pragma unroll
        for (int dm = 0; dm < 2; dm++)
#pragma unroll
            for (int g = 0; g < 4; g++) {
                int d0 = dm * 32 + 8 * g + 4 * hi;
                ushort4 pk;
                pk.x = f2bf(oacc[dm][4 * g + 0] * invl);
                pk.y = f2bf(oacc[dm][4 * g + 1] * invl);
                pk.z = f2bf(oacc[dm][4 * g + 2] * invl);
                pk.w = f2bf(oacc[dm][4 * g + 3] * invl);
                *(ushort4*)(o + ((size_t)b_ * SEQ + qg) * HID + h_ * HD + d0) = pk;
            }
    }
}

// ---------------------------------------------------------------------------
extern "C" void kernel_launch(void* const* d_in, const int* in_sizes, int n_in,
                              void* d_out, int out_size, void* d_ws, size_t ws_size,
                              hipStream_t stream)
{
    const float* x  = (const float*)d_in[0];
    const float* Wq = (const float*)d_in[1];
    const float* bq = (const float*)d_in[2];
    const float* Wk = (const float*)d_in[3];
    const float* bk = (const float*)d_in[4];
    const float* Wv = (const float*)d_in[5];
    const float* bv = (const float*)d_in[6];
    const float* Wo = (const float*)d_in[7];
    const float* bo = (const float*)d_in[8];
    float* out = (float*)d_out;

    const size_t TE = (size_t)M_TOT * HID;   // 8,388,608
    const size_t WE = (size_t)HID * HID;     // 1,048,576
    ushort* qws = (ushort*)d_ws;   // Q^T [B,H,D,S]
    ushort* kws = qws + TE;        // K   [B,H,S,D]
    ushort* vws = kws + TE;        // V^T [B,H,D,S]
    ushort* xbf = vws + TE;        // x in bf16; reused as attn output
    ushort* aws = xbf;
    ushort* wqb = xbf + TE;
    ushort* wkb = wqb + WE;
    ushort* wvb = wkb + WE;
    ushort* wob = wvb + WE;        // total ws: 75.5 MB

    convert_bf16<<<(X_F4 + 4 * W_F4) / 256, 256, 0, stream>>>(
        x, Wq, Wk, Wv, Wo, xbf, wqb, wkb, wvb, wob);

    dim3 g1(M_TOT / BM, HID / BN, 3);
    gemm_bf<1><<<g1, 256, 0, stream>>>(xbf, wqb, wkb, wvb, bq, bk, bv,
                                       qws, kws, vws, nullptr);

    dim3 g2(SEQ / 128, BATCH * NH, 1);
    attn_flash<<<g2, 256, 0, stream>>>(qws, kws, vws, aws);

    dim3 g3(M_TOT / BM, HID / BN, 1);
    gemm_bf<0><<<g3, 256, 0, stream>>>(aws, wob, wob, wob, bo, bo, bo,
                                       nullptr, nullptr, nullptr, out);
}

// Round 12
// 340.258 us; speedup vs baseline: 1.0611x; 1.0611x over previous
//
#include <hip/hip_runtime.h>
#include <hip/hip_bf16.h>

// MHA forward on MI355X: B=4, S=2048, H=16, D=64, HIDDEN=1024. fp32 in/out.
// Stage 0: convert x, Wq, Wk, Wv, Wo to bf16 in workspace (one pass).
// Stage 1: QKV GEMM (global_load_lds staging, XOR-swizzled LDS).
//          Q -> TRANSPOSED [B,H,D,S], PRE-SCALED by log2(e)/sqrt(D);
//          K -> [B,H,S,D]; V -> TRANSPOSED [B,H,D,S].
// Stage 2: flash attention, 32x32x16 MFMA. R12: K read from global into a
//          REGISTER double-buffer -- tile t+1's 8 K-frags are loaded right
//          after the barrier of tile t and consumed next iteration, so the
//          L1/L2 latency R11 exposed (MfmaUtil 14.7%, VALUBusy 20.6%: both
//          pipes idle = latency-bound) is covered by a full tile of compute.
//          LDS still carries only V (dbuf, 16 KB).
// Stage 3: out = attn @ Wo^T + bo (fp32 out).

typedef __attribute__((ext_vector_type(8)))  short short8;    // 8 x bf16
typedef __attribute__((ext_vector_type(4)))  float floatx4;   // 16x16 C/D
typedef __attribute__((ext_vector_type(16))) float floatx16;  // 32x32 C/D

#define HID 1024
#define SEQ 2048
#define BATCH 4
#define NH 16
#define HD 64
#define M_TOT (BATCH * SEQ)   // 8192

#define BM 128
#define BN 128
#define BK 64

#define SCALE2 0.1803368801111204f   // (1/sqrt(64)) * log2(e)

typedef const __attribute__((address_space(1))) void g_void;
typedef __attribute__((address_space(3))) void lds_void;

static __device__ __forceinline__ ushort f2bf(float f) {
    union { float f; unsigned int u; } v;
    v.f = f;
    unsigned int u = v.u;
    return (ushort)((u + 0x7fffu + ((u >> 16) & 1u)) >> 16);  // RNE
}
static __device__ __forceinline__ ushort4 f4tobf(float4 f) {
    ushort4 r;
    r.x = f2bf(f.x); r.y = f2bf(f.y); r.z = f2bf(f.z); r.w = f2bf(f.w);
    return r;
}
static __device__ __forceinline__ unsigned int fbits(float f) {
    union { float f; unsigned int u; } v; v.f = f; return v.u;
}

// ---------------------------------------------------------------------------
// Stage 0: fp32 -> bf16 conversion for x and the four weight matrices.
// ---------------------------------------------------------------------------
#define X_F4 (M_TOT * HID / 4)   // 2,097,152 float4s
#define W_F4 (HID * HID / 4)     //   262,144 float4s

__global__ __launch_bounds__(256) void convert_bf16(
    const float* __restrict__ x,
    const float* __restrict__ wq, const float* __restrict__ wk,
    const float* __restrict__ wv, const float* __restrict__ wo,
    ushort* __restrict__ xo,
    ushort* __restrict__ wqo, ushort* __restrict__ wko,
    ushort* __restrict__ wvo, ushort* __restrict__ woo)
{
    long i = (long)blockIdx.x * 256 + threadIdx.x;
    const float4* src; ushort4* dst; long off;
    if (i < X_F4)                  { src = (const float4*)x;  dst = (ushort4*)xo;  off = i; }
    else if (i < X_F4 + W_F4)      { src = (const float4*)wq; dst = (ushort4*)wqo; off = i - X_F4; }
    else if (i < X_F4 + 2 * W_F4)  { src = (const float4*)wk; dst = (ushort4*)wko; off = i - X_F4 - W_F4; }
    else if (i < X_F4 + 3 * W_F4)  { src = (const float4*)wv; dst = (ushort4*)wvo; off = i - X_F4 - 2 * W_F4; }
    else                           { src = (const float4*)wo; dst = (ushort4*)woo; off = i - X_F4 - 3 * W_F4; }
    dst[off] = f4tobf(src[off]);
}

// ---------------------------------------------------------------------------
// bf16 NT GEMM, m97 structure (global_load_lds width-16, XOR chunk swizzle).
// MODE 1: z=0 -> Q^T [B,H,D,S] pre-scaled; z=1 -> K [B,H,S,D]; z=2 -> V^T.
// MODE 0: fp32 row-major output (of).
// ---------------------------------------------------------------------------
template <int MODE>
__global__ __launch_bounds__(256) void gemm_bf(
    const ushort* __restrict__ A,
    const ushort* __restrict__ W0, const ushort* __restrict__ W1,
    const ushort* __restrict__ W2,
    const float* __restrict__ b0, const float* __restrict__ b1,
    const float* __restrict__ b2,
    ushort* __restrict__ o0, ushort* __restrict__ o1, ushort* __restrict__ o2,
    float* __restrict__ of)
{
    __shared__ ushort As[BM * BK];   // 16 KB
    __shared__ ushort Bs[BN * BK];   // 16 KB

    const int tid  = threadIdx.x;
    const int wave = tid >> 6;
    const int lane = tid & 63;
    const int l16  = lane & 15;
    const int lq   = lane >> 4;

    const int m0 = blockIdx.x * BM;
    const int n0 = blockIdx.y * BN;
    const int z  = (MODE == 1) ? blockIdx.z : 0;

    const ushort* W   = (z == 0) ? W0 : (z == 1) ? W1 : W2;
    const float* bias = (z == 0) ? b0 : (z == 1) ? b1 : b2;

    const int wm = (wave & 1) * 64;
    const int wn = (wave >> 1) * 64;

    const int srow = lane >> 3;
    const int schk = (lane & 7) ^ srow;
    const ushort* gA = A + (size_t)(m0 + wave * 32 + srow) * HID + schk * 8;
    const ushort* gW = W + (size_t)(n0 + wave * 32 + srow) * HID + schk * 8;
    ushort* lA = As + (wave * 32) * BK;
    ushort* lB = Bs + (wave * 32) * BK;

    floatx4 acc[4][4];
#pragma unroll
    for (int i = 0; i < 4; i++)
#pragma unroll
        for (int j = 0; j < 4; j++)
            acc[i][j] = (floatx4){0.f, 0.f, 0.f, 0.f};

    for (int k0 = 0; k0 < HID; k0 += BK) {
        __syncthreads();
#pragma unroll
        for (int i = 0; i < 4; i++) {
            __builtin_amdgcn_global_load_lds(
                (g_void*)(gA + (size_t)(8 * i) * HID + k0),
                (lds_void*)(lA + (8 * i) * BK), 16, 0, 0);
            __builtin_amdgcn_global_load_lds(
                (g_void*)(gW + (size_t)(8 * i) * HID + k0),
                (lds_void*)(lB + (8 * i) * BK), 16, 0, 0);
        }
        __syncthreads();

        const int sw = l16 & 7;
#pragma unroll
        for (int kk8 = 0; kk8 < 8; kk8 += 4) {
            short8 a[4], b[4];
#pragma unroll
            for (int i = 0; i < 4; i++)
                a[i] = *(const short8*)(&As[(wm + i * 16 + l16) * BK + ((lq + kk8) ^ sw) * 8]);
#pragma unroll
            for (int j = 0; j < 4; j++)
                b[j] = *(const short8*)(&Bs[(wn + j * 16 + l16) * BK + ((lq + kk8) ^ sw) * 8]);
#pragma unroll
            for (int i = 0; i < 4; i++)
#pragma unroll
                for (int j = 0; j < 4; j++)
                    acc[i][j] = __builtin_amdgcn_mfma_f32_16x16x32_bf16(
                        a[i], b[j], acc[i][j], 0, 0, 0);
        }
    }

    if (MODE == 0) {
#pragma unroll
        for (int j = 0; j < 4; j++) {
            int n = n0 + wn + j * 16 + l16;
            float bv = bias[n];
#pragma unroll
            for (int i = 0; i < 4; i++)
#pragma unroll
                for (int r = 0; r < 4; r++) {
                    int m = m0 + wm + i * 16 + lq * 4 + r;
                    of[(size_t)m * HID + n] = acc[i][j][r] + bv;
                }
        }
    } else if (z == 1) {
        // K: [B,H,S,D] scatter
        ushort* out = o1;
#pragma unroll
        for (int j = 0; j < 4; j++) {
            int n = n0 + wn + j * 16 + l16;
            float bv = bias[n];
            int h_ = n >> 6, d_ = n & (HD - 1);
#pragma unroll
            for (int i = 0; i < 4; i++)
#pragma unroll
                for (int r = 0; r < 4; r++) {
                    int m = m0 + wm + i * 16 + lq * 4 + r;
                    int b_ = m >> 11, s_ = m & (SEQ - 1);
                    out[(((size_t)b_ * NH + h_) * SEQ + s_) * HD + d_] =
                        f2bf(acc[i][j][r] + bv);
                }
        }
    } else {
        // z==0 (Q^T, pre-scaled) / z==2 (V^T): [B,H,D,S], 8B vector stores
        ushort* out = (z == 0) ? o0 : o2;
        const float sc = (z == 0) ? SCALE2 : 1.0f;
#pragma unroll
        for (int j = 0; j < 4; j++) {
            int n = n0 + wn + j * 16 + l16;
            float bv = bias[n];
            int h_ = n >> 6, d_ = n & (HD - 1);
#pragma unroll
            for (int i = 0; i < 4; i++) {
                int m = m0 + wm + i * 16 + lq * 4;
                int b_ = m >> 11, s0 = m & (SEQ - 1);
                ushort4 pk;
                pk.x = f2bf((acc[i][j][0] + bv) * sc);
                pk.y = f2bf((acc[i][j][1] + bv) * sc);
                pk.z = f2bf((acc[i][j][2] + bv) * sc);
                pk.w = f2bf((acc[i][j][3] + bv) * sc);
                *(ushort4*)(out + (((size_t)b_ * NH + h_) * HD + d_) * SEQ + s0) = pk;
            }
        }
    }
}

// ---------------------------------------------------------------------------
// Stage 2: flash attention, 32x32x16 MFMA, fixed-base softmax.
// Block = 128 Q rows of one (b,h); wave owns 32 q (q = l32).
// K: global -> REGISTER double-buffer, loads for tile t+1 issued at top of
// tile t (full tile of compute in flight). V^T: LDS dbuf via global_load_lds.
// QK: S^T = mfma32(A=K, B=Q); C/D col=q=lane&31, row=(reg&3)+8*(reg>>2)+4*hi.
// PV: O^T = mfma32(A=V^T, B=P^T); P B-frag built with one shfl_xor(32) pair
// + cndmasks per 16-s chunk.
// ---------------------------------------------------------------------------
__global__ __launch_bounds__(256, 3) void attn_flash(
    const ushort* __restrict__ q, const ushort* __restrict__ k,
    const ushort* __restrict__ v, ushort* __restrict__ o)
{
    __shared__ ushort Vs[2 * 64 * 64];  // 16 KB, [buf][d][s_local] swizzled

    const int tid  = threadIdx.x;
    const int wave = tid >> 6;
    const int lane = tid & 63;
    const int l32  = lane & 31;
    const int hi   = lane >> 5;
    const int e    = l32 & 7;

    const int qb = blockIdx.x;   // 0..15 (128-row Q tiles)
    const int bh = blockIdx.y;   // 0..63
    const int b_ = bh >> 4, h_ = bh & 15;

    const size_t base = (size_t)bh * SEQ * HD;
    const ushort* Qt = q + base;   // [d][s]
    const ushort* K  = k + base;   // [s][d]
    const ushort* Vt = v + base;   // [d][s]

    const int q0 = qb * 128 + wave * 32;

    // Q B-frags: B[n = q0+l32][k = d = dk*16 + hi*8 + jj], one-time scalar loads
    short8 qf[4];
#pragma unroll
    for (int dk = 0; dk < 4; dk++)
#pragma unroll
        for (int jj = 0; jj < 8; jj++)
            qf[dk][jj] = (short)Qt[(size_t)(dk * 16 + hi * 8 + jj) * SEQ + q0 + l32];

    // per-lane K fragment pointer: row (l32), d-chunk (dk*16 + hi*8)
    const ushort* gKf = K + (size_t)l32 * HD + hi * 8;

    const int srow = lane >> 3;
    const int schk = (lane & 7) ^ srow;
    const ushort* gV = Vt + (size_t)(wave * 8 + srow) * SEQ + schk * 8;

    floatx16 oacc[2];
#pragma unroll
    for (int dm = 0; dm < 2; dm++)
#pragma unroll
        for (int r = 0; r < 16; r++) oacc[dm][r] = 0.f;
    float l_ = 0.f;

    // K register double-buffer: preload tile 0
    short8 kc[2][4], kn[2][4];
#pragma unroll
    for (int mt = 0; mt < 2; mt++)
#pragma unroll
        for (int dk = 0; dk < 4; dk++)
            kc[mt][dk] = *(const short8*)(gKf + (size_t)(mt * 32) * HD + dk * 16);

    // prologue: stage V tile 0 into buffer 0
#pragma unroll
    for (int i = 0; i < 2; i++) {
        __builtin_amdgcn_global_load_lds(
            (g_void*)(gV + (size_t)(i * 32) * SEQ),
            (lds_void*)(Vs + (i * 32 + wave * 8) * 64), 16, 0, 0);
    }

    for (int t = 0; t < SEQ / 64; t++) {
        __syncthreads();   // V tile t staged; prior reads of the other buf done

        if (t + 1 < SEQ / 64) {
            const int nb = (t + 1) & 1;
#pragma unroll
            for (int i = 0; i < 2; i++) {
                __builtin_amdgcn_global_load_lds(
                    (g_void*)(gV + (size_t)(i * 32) * SEQ + (t + 1) * 64),
                    (lds_void*)(Vs + nb * 4096 + (i * 32 + wave * 8) * 64), 16, 0, 0);
            }
            // K prefetch for tile t+1 (in flight across exp+PV of tile t)
#pragma unroll
            for (int mt = 0; mt < 2; mt++)
#pragma unroll
                for (int dk = 0; dk < 4; dk++)
                    kn[mt][dk] = *(const short8*)(
                        gKf + (size_t)((t + 1) * 64 + mt * 32) * HD + dk * 16);
        }

        const ushort* Vb = Vs + (t & 1) * 4096;

        // S^T: 2 m-tiles of 32 s x 32 q, from the K register buffer
        floatx16 st[2];
#pragma unroll
        for (int mt = 0; mt < 2; mt++) {
#pragma unroll
            for (int r = 0; r < 16; r++) st[mt][r] = 0.f;
#pragma unroll
            for (int dk = 0; dk < 4; dk++)
                st[mt] = __builtin_amdgcn_mfma_f32_32x32x16_bf16(
                    kc[mt][dk], qf[dk], st[mt], 0, 0, 0);
        }

        // p = exp2(s) (raw v_exp_f32); pack bf16 pairs; accumulate l
        unsigned int P32[2][8];
        float rs = 0.f;
#pragma unroll
        for (int mt = 0; mt < 2; mt++) {
            float p[16];
#pragma unroll
            for (int r = 0; r < 16; r++) {
                p[r] = __builtin_amdgcn_exp2f(st[mt][r]);
                rs += p[r];
            }
#pragma unroll
            for (int rr = 0; rr < 8; rr++)
                P32[mt][rr] = __builtin_amdgcn_perm(
                    fbits(p[2 * rr + 1]), fbits(p[2 * rr]), 0x07060302u);
        }
        l_ += rs;

        // PV: per 16-s chunk sc, build P B-frag via lane^32 exchange.
#pragma unroll
        for (int sc = 0; sc < 4; sc++) {
            const int mt = sc >> 1;
            const int bse = 4 * (sc & 1);
            unsigned int X = P32[mt][bse],     Y = P32[mt][bse + 1];
            unsigned int Z = P32[mt][bse + 2], W = P32[mt][bse + 3];
            unsigned int sendA = hi ? X : Z;
            unsigned int sendB = hi ? Y : W;
            unsigned int recvA = (unsigned int)__shfl_xor((int)sendA, 32, 64);
            unsigned int recvB = (unsigned int)__shfl_xor((int)sendB, 32, 64);
            unsigned int u0 = hi ? recvA : X;
            unsigned int u1 = hi ? recvB : Y;
            unsigned int u2 = hi ? Z : recvA;
            unsigned int u3 = hi ? W : recvB;
            union { unsigned int u[4]; short8 s; } pfr;
            pfr.u[0] = u0; pfr.u[1] = u1; pfr.u[2] = u2; pfr.u[3] = u3;
#pragma unroll
            for (int dm = 0; dm < 2; dm++) {
                short8 vf = *(const short8*)(
                    &Vb[(dm * 32 + l32) * 64 + ((2 * sc + hi) ^ e) * 8]);
                oacc[dm] = __builtin_amdgcn_mfma_f32_32x32x16_bf16(
                    vf, pfr.s, oacc[dm], 0, 0, 0);
            }
        }

        // rotate K register buffer
        if (t + 1 < SEQ / 64) {
#pragma unroll
            for (int mt = 0; mt < 2; mt++)
#pragma unroll
                for (int dk = 0; dk < 4; dk++)
                    kc[mt][dk] = kn[mt][dk];
        }
    }

    // each lane covers half the s-range; partner lane^32 has the other half
    l_ += __shfl_xor(l_, 32, 64);

    {
        const int qg = q0 + l32;
        const float invl = 1.0f / l_;
#pragma unroll
        for (int dm = 0; dm < 2; dm++)
#pragma unroll
            for (int g = 0; g < 4; g++) {
                int d0 = dm * 32 + 8 * g + 4 * hi;
                ushort4 pk;
                pk.x = f2bf(oacc[dm][4 * g + 0] * invl);
                pk.y = f2bf(oacc[dm][4 * g + 1] * invl);
                pk.z = f2bf(oacc[dm][4 * g + 2] * invl);
                pk.w = f2bf(oacc[dm][4 * g + 3] * invl);
                *(ushort4*)(o + ((size_t)b_ * SEQ + qg) * HID + h_ * HD + d0) = pk;
            }
    }
}

// ---------------------------------------------------------------------------
extern "C" void kernel_launch(void* const* d_in, const int* in_sizes, int n_in,
                              void* d_out, int out_size, void* d_ws, size_t ws_size,
                              hipStream_t stream)
{
    const float* x  = (const float*)d_in[0];
    const float* Wq = (const float*)d_in[1];
    const float* bq = (const float*)d_in[2];
    const float* Wk = (const float*)d_in[3];
    const float* bk = (const float*)d_in[4];
    const float* Wv = (const float*)d_in[5];
    const float* bv = (const float*)d_in[6];
    const float* Wo = (const float*)d_in[7];
    const float* bo = (const float*)d_in[8];
    float* out = (float*)d_out;

    const size_t TE = (size_t)M_TOT * HID;   // 8,388,608
    const size_t WE = (size_t)HID * HID;     // 1,048,576
    ushort* qws = (ushort*)d_ws;   // Q^T [B,H,D,S]
    ushort* kws = qws + TE;        // K   [B,H,S,D]
    ushort* vws = kws + TE;        // V^T [B,H,D,S]
    ushort* xbf = vws + TE;        // x in bf16; reused as attn output
    ushort* aws = xbf;
    ushort* wqb = xbf + TE;
    ushort* wkb = wqb + WE;
    ushort* wvb = wkb + WE;
    ushort* wob = wvb + WE;        // total ws: 75.5 MB

    convert_bf16<<<(X_F4 + 4 * W_F4) / 256, 256, 0, stream>>>(
        x, Wq, Wk, Wv, Wo, xbf, wqb, wkb, wvb, wob);

    dim3 g1(M_TOT / BM, HID / BN, 3);
    gemm_bf<1><<<g1, 256, 0, stream>>>(xbf, wqb, wkb, wvb, bq, bk, bv,
                                       qws, kws, vws, nullptr);

    dim3 g2(SEQ / 128, BATCH * NH, 1);
    attn_flash<<<g2, 256, 0, stream>>>(qws, kws, vws, aws);

    dim3 g3(M_TOT / BM, HID / BN, 1);
    gemm_bf<0><<<g3, 256, 0, stream>>>(aws, wob, wob, wob, bo, bo, bo,
                                       nullptr, nullptr, nullptr, out);
}

// Round 13
// 272.469 us; speedup vs baseline: 1.3251x; 1.2488x over previous
//
#include <hip/hip_runtime.h>
#include <hip/hip_bf16.h>

// MHA forward on MI355X: B=4, S=2048, H=16, D=64, HIDDEN=1024. fp32 in/out.
// Stage 0: convert x, Wq, Wk, Wv, Wo to bf16 in workspace (one pass).
// Stage 1: QKV GEMM (global_load_lds staging, XOR-swizzled LDS).
//          Q -> TRANSPOSED [B,H,D,S], PRE-SCALED by log2(e)/sqrt(D);
//          K -> [B,H,S,D]; V -> TRANSPOSED [B,H,D,S].
// Stage 2: flash attention, 32x32x16 MFMA, K+V staged in LDS (R10 structure —
//          R11/R12's direct-global K was latency/divergence-bound, reverted).
//          R13: 64 q per wave, 128-thread blocks (2 waves) -- each staged K/V
//          tile is read by 2 waves not 4, cutting LDS read traffic 40%/q
//          (R10 audit: LDS ~61 of 95 us). Two f-chains/wave double MFMA ILP.
// Stage 3: out = attn @ Wo^T + bo (fp32 out).

typedef __attribute__((ext_vector_type(8)))  short short8;    // 8 x bf16
typedef __attribute__((ext_vector_type(4)))  float floatx4;   // 16x16 C/D
typedef __attribute__((ext_vector_type(16))) float floatx16;  // 32x32 C/D

#define HID 1024
#define SEQ 2048
#define BATCH 4
#define NH 16
#define HD 64
#define M_TOT (BATCH * SEQ)   // 8192

#define BM 128
#define BN 128
#define BK 64

#define SCALE2 0.1803368801111204f   // (1/sqrt(64)) * log2(e)

typedef const __attribute__((address_space(1))) void g_void;
typedef __attribute__((address_space(3))) void lds_void;

static __device__ __forceinline__ ushort f2bf(float f) {
    union { float f; unsigned int u; } v;
    v.f = f;
    unsigned int u = v.u;
    return (ushort)((u + 0x7fffu + ((u >> 16) & 1u)) >> 16);  // RNE
}
static __device__ __forceinline__ ushort4 f4tobf(float4 f) {
    ushort4 r;
    r.x = f2bf(f.x); r.y = f2bf(f.y); r.z = f2bf(f.z); r.w = f2bf(f.w);
    return r;
}
static __device__ __forceinline__ unsigned int fbits(float f) {
    union { float f; unsigned int u; } v; v.f = f; return v.u;
}

// ---------------------------------------------------------------------------
// Stage 0: fp32 -> bf16 conversion for x and the four weight matrices.
// ---------------------------------------------------------------------------
#define X_F4 (M_TOT * HID / 4)   // 2,097,152 float4s
#define W_F4 (HID * HID / 4)     //   262,144 float4s

__global__ __launch_bounds__(256) void convert_bf16(
    const float* __restrict__ x,
    const float* __restrict__ wq, const float* __restrict__ wk,
    const float* __restrict__ wv, const float* __restrict__ wo,
    ushort* __restrict__ xo,
    ushort* __restrict__ wqo, ushort* __restrict__ wko,
    ushort* __restrict__ wvo, ushort* __restrict__ woo)
{
    long i = (long)blockIdx.x * 256 + threadIdx.x;
    const float4* src; ushort4* dst; long off;
    if (i < X_F4)                  { src = (const float4*)x;  dst = (ushort4*)xo;  off = i; }
    else if (i < X_F4 + W_F4)      { src = (const float4*)wq; dst = (ushort4*)wqo; off = i - X_F4; }
    else if (i < X_F4 + 2 * W_F4)  { src = (const float4*)wk; dst = (ushort4*)wko; off = i - X_F4 - W_F4; }
    else if (i < X_F4 + 3 * W_F4)  { src = (const float4*)wv; dst = (ushort4*)wvo; off = i - X_F4 - 2 * W_F4; }
    else                           { src = (const float4*)wo; dst = (ushort4*)woo; off = i - X_F4 - 3 * W_F4; }
    dst[off] = f4tobf(src[off]);
}

// ---------------------------------------------------------------------------
// bf16 NT GEMM, m97 structure (global_load_lds width-16, XOR chunk swizzle).
// MODE 1: z=0 -> Q^T [B,H,D,S] pre-scaled; z=1 -> K [B,H,S,D]; z=2 -> V^T.
// MODE 0: fp32 row-major output (of).
// ---------------------------------------------------------------------------
template <int MODE>
__global__ __launch_bounds__(256) void gemm_bf(
    const ushort* __restrict__ A,
    const ushort* __restrict__ W0, const ushort* __restrict__ W1,
    const ushort* __restrict__ W2,
    const float* __restrict__ b0, const float* __restrict__ b1,
    const float* __restrict__ b2,
    ushort* __restrict__ o0, ushort* __restrict__ o1, ushort* __restrict__ o2,
    float* __restrict__ of)
{
    __shared__ ushort As[BM * BK];   // 16 KB
    __shared__ ushort Bs[BN * BK];   // 16 KB

    const int tid  = threadIdx.x;
    const int wave = tid >> 6;
    const int lane = tid & 63;
    const int l16  = lane & 15;
    const int lq   = lane >> 4;

    const int m0 = blockIdx.x * BM;
    const int n0 = blockIdx.y * BN;
    const int z  = (MODE == 1) ? blockIdx.z : 0;

    const ushort* W   = (z == 0) ? W0 : (z == 1) ? W1 : W2;
    const float* bias = (z == 0) ? b0 : (z == 1) ? b1 : b2;

    const int wm = (wave & 1) * 64;
    const int wn = (wave >> 1) * 64;

    const int srow = lane >> 3;
    const int schk = (lane & 7) ^ srow;
    const ushort* gA = A + (size_t)(m0 + wave * 32 + srow) * HID + schk * 8;
    const ushort* gW = W + (size_t)(n0 + wave * 32 + srow) * HID + schk * 8;
    ushort* lA = As + (wave * 32) * BK;
    ushort* lB = Bs + (wave * 32) * BK;

    floatx4 acc[4][4];
#pragma unroll
    for (int i = 0; i < 4; i++)
#pragma unroll
        for (int j = 0; j < 4; j++)
            acc[i][j] = (floatx4){0.f, 0.f, 0.f, 0.f};

    for (int k0 = 0; k0 < HID; k0 += BK) {
        __syncthreads();
#pragma unroll
        for (int i = 0; i < 4; i++) {
            __builtin_amdgcn_global_load_lds(
                (g_void*)(gA + (size_t)(8 * i) * HID + k0),
                (lds_void*)(lA + (8 * i) * BK), 16, 0, 0);
            __builtin_amdgcn_global_load_lds(
                (g_void*)(gW + (size_t)(8 * i) * HID + k0),
                (lds_void*)(lB + (8 * i) * BK), 16, 0, 0);
        }
        __syncthreads();

        const int sw = l16 & 7;
#pragma unroll
        for (int kk8 = 0; kk8 < 8; kk8 += 4) {
            short8 a[4], b[4];
#pragma unroll
            for (int i = 0; i < 4; i++)
                a[i] = *(const short8*)(&As[(wm + i * 16 + l16) * BK + ((lq + kk8) ^ sw) * 8]);
#pragma unroll
            for (int j = 0; j < 4; j++)
                b[j] = *(const short8*)(&Bs[(wn + j * 16 + l16) * BK + ((lq + kk8) ^ sw) * 8]);
#pragma unroll
            for (int i = 0; i < 4; i++)
#pragma unroll
                for (int j = 0; j < 4; j++)
                    acc[i][j] = __builtin_amdgcn_mfma_f32_16x16x32_bf16(
                        a[i], b[j], acc[i][j], 0, 0, 0);
        }
    }

    if (MODE == 0) {
#pragma unroll
        for (int j = 0; j < 4; j++) {
            int n = n0 + wn + j * 16 + l16;
            float bv = bias[n];
#pragma unroll
            for (int i = 0; i < 4; i++)
#pragma unroll
                for (int r = 0; r < 4; r++) {
                    int m = m0 + wm + i * 16 + lq * 4 + r;
                    of[(size_t)m * HID + n] = acc[i][j][r] + bv;
                }
        }
    } else if (z == 1) {
        // K: [B,H,S,D] scatter
        ushort* out = o1;
#pragma unroll
        for (int j = 0; j < 4; j++) {
            int n = n0 + wn + j * 16 + l16;
            float bv = bias[n];
            int h_ = n >> 6, d_ = n & (HD - 1);
#pragma unroll
            for (int i = 0; i < 4; i++)
#pragma unroll
                for (int r = 0; r < 4; r++) {
                    int m = m0 + wm + i * 16 + lq * 4 + r;
                    int b_ = m >> 11, s_ = m & (SEQ - 1);
                    out[(((size_t)b_ * NH + h_) * SEQ + s_) * HD + d_] =
                        f2bf(acc[i][j][r] + bv);
                }
        }
    } else {
        // z==0 (Q^T, pre-scaled) / z==2 (V^T): [B,H,D,S], 8B vector stores
        ushort* out = (z == 0) ? o0 : o2;
        const float sc = (z == 0) ? SCALE2 : 1.0f;
#pragma unroll
        for (int j = 0; j < 4; j++) {
            int n = n0 + wn + j * 16 + l16;
            float bv = bias[n];
            int h_ = n >> 6, d_ = n & (HD - 1);
#pragma unroll
            for (int i = 0; i < 4; i++) {
                int m = m0 + wm + i * 16 + lq * 4;
                int b_ = m >> 11, s0 = m & (SEQ - 1);
                ushort4 pk;
                pk.x = f2bf((acc[i][j][0] + bv) * sc);
                pk.y = f2bf((acc[i][j][1] + bv) * sc);
                pk.z = f2bf((acc[i][j][2] + bv) * sc);
                pk.w = f2bf((acc[i][j][3] + bv) * sc);
                *(ushort4*)(out + (((size_t)b_ * NH + h_) * HD + d_) * SEQ + s0) = pk;
            }
        }
    }
}

// ---------------------------------------------------------------------------
// Stage 2: flash attention, 32x32x16 MFMA, fixed-base softmax, K/V LDS dbuf.
// 128-thread block = 2 waves x 64 q (f=0,1 fragments of 32 q each).
// Q^T (pre-scaled) [B,H,D,S]; K [B,H,S,D]; V^T [B,H,D,S]. Out bf16 [B,S,H*D].
// QK: S^T = mfma32(A=K, B=Q); C/D col=q=lane&31, row=(reg&3)+8*(reg>>2)+4*hi.
// PV: O^T = mfma32(A=V^T, B=P^T); P B-frag built per f with one shfl_xor(32)
// pair + cndmasks per 16-s chunk (R10-verified algebra).
// ---------------------------------------------------------------------------
__global__ __launch_bounds__(128, 2) void attn_flash(
    const ushort* __restrict__ q, const ushort* __restrict__ k,
    const ushort* __restrict__ v, ushort* __restrict__ o)
{
    __shared__ ushort Ks[2 * 64 * 64];  // 16 KB, [buf][s_local][d] swizzled
    __shared__ ushort Vs[2 * 64 * 64];  // 16 KB, [buf][d][s_local] swizzled

    const int tid  = threadIdx.x;       // 0..127
    const int wave = tid >> 6;          // 0..1
    const int lane = tid & 63;
    const int l32  = lane & 31;
    const int hi   = lane >> 5;
    const int e    = l32 & 7;

    const int qb = blockIdx.x;   // 0..15 (128-row Q tiles)
    const int bh = blockIdx.y;   // 0..63
    const int b_ = bh >> 4, h_ = bh & 15;

    const size_t base = (size_t)bh * SEQ * HD;
    const ushort* Qt = q + base;   // [d][s]
    const ushort* K  = k + base;   // [s][d]
    const ushort* Vt = v + base;   // [d][s]

    const int q0w = qb * 128 + wave * 64;

    // Q B-frags: B[n = q0w + f*32 + l32][k = d = dk*16 + hi*8 + jj]
    short8 qf[2][4];
#pragma unroll
    for (int f = 0; f < 2; f++)
#pragma unroll
        for (int dk = 0; dk < 4; dk++)
#pragma unroll
            for (int jj = 0; jj < 8; jj++)
                qf[f][dk][jj] =
                    (short)Qt[(size_t)(dk * 16 + hi * 8 + jj) * SEQ + q0w + f * 32 + l32];

    // staging: per wave, 4 issues x (8 rows x 8 chunks); XOR chunk swizzle
    const int srow = lane >> 3;          // 0..7
    const int schk = (lane & 7) ^ srow;
    const ushort* gK = K  + (size_t)(wave * 8 + srow) * HD  + schk * 8;
    const ushort* gV = Vt + (size_t)(wave * 8 + srow) * SEQ + schk * 8;

    floatx16 oacc[2][2];
#pragma unroll
    for (int f = 0; f < 2; f++)
#pragma unroll
        for (int dm = 0; dm < 2; dm++)
#pragma unroll
            for (int r = 0; r < 16; r++) oacc[f][dm][r] = 0.f;
    float l_[2] = {0.f, 0.f};

    // prologue: stage tile 0 into buffer 0 (rows i*16 + wave*8 + srow)
#pragma unroll
    for (int i = 0; i < 4; i++) {
        __builtin_amdgcn_global_load_lds(
            (g_void*)(gK + (size_t)(i * 16) * HD),
            (lds_void*)(Ks + (i * 16 + wave * 8) * 64), 16, 0, 0);
        __builtin_amdgcn_global_load_lds(
            (g_void*)(gV + (size_t)(i * 16) * SEQ),
            (lds_void*)(Vs + (i * 16 + wave * 8) * 64), 16, 0, 0);
    }

    for (int t = 0; t < SEQ / 64; t++) {
        __syncthreads();   // tile t staged; prior reads of the other buf done

        if (t + 1 < SEQ / 64) {
            const int nb = (t + 1) & 1;
#pragma unroll
            for (int i = 0; i < 4; i++) {
                __builtin_amdgcn_global_load_lds(
                    (g_void*)(gK + (size_t)((t + 1) * 64 + i * 16) * HD),
                    (lds_void*)(Ks + nb * 4096 + (i * 16 + wave * 8) * 64), 16, 0, 0);
                __builtin_amdgcn_global_load_lds(
                    (g_void*)(gV + (size_t)(i * 16) * SEQ + (t + 1) * 64),
                    (lds_void*)(Vs + nb * 4096 + (i * 16 + wave * 8) * 64), 16, 0, 0);
            }
        }

        const ushort* Kb = Ks + (t & 1) * 4096;
        const ushort* Vb = Vs + (t & 1) * 4096;

        // S^T: 2 m-tiles x 2 f; each kf fragment feeds both f-chains
        floatx16 st[2][2];
#pragma unroll
        for (int f = 0; f < 2; f++)
#pragma unroll
            for (int mt = 0; mt < 2; mt++)
#pragma unroll
                for (int r = 0; r < 16; r++) st[f][mt][r] = 0.f;
#pragma unroll
        for (int mt = 0; mt < 2; mt++) {
#pragma unroll
            for (int dk = 0; dk < 4; dk++) {
                short8 kf = *(const short8*)(
                    &Kb[(mt * 32 + l32) * 64 + ((2 * dk + hi) ^ e) * 8]);
                st[0][mt] = __builtin_amdgcn_mfma_f32_32x32x16_bf16(
                    kf, qf[0][dk], st[0][mt], 0, 0, 0);
                st[1][mt] = __builtin_amdgcn_mfma_f32_32x32x16_bf16(
                    kf, qf[1][dk], st[1][mt], 0, 0, 0);
            }
        }

        // p = exp2(s) (raw v_exp_f32); pack bf16 pairs; accumulate l
        unsigned int P32[2][2][8];
#pragma unroll
        for (int f = 0; f < 2; f++) {
            float rs = 0.f;
#pragma unroll
            for (int mt = 0; mt < 2; mt++) {
                float p[16];
#pragma unroll
                for (int r = 0; r < 16; r++) {
                    p[r] = __builtin_amdgcn_exp2f(st[f][mt][r]);
                    rs += p[r];
                }
#pragma unroll
                for (int rr = 0; rr < 8; rr++)
                    P32[f][mt][rr] = __builtin_amdgcn_perm(
                        fbits(p[2 * rr + 1]), fbits(p[2 * rr]), 0x07060302u);
            }
            l_[f] += rs;
        }

        // PV: per 16-s chunk sc, build P B-frags (both f) via lane^32 exchange;
        // each vf fragment feeds both f-chains.
#pragma unroll
        for (int sc = 0; sc < 4; sc++) {
            const int mt = sc >> 1;
            const int bse = 4 * (sc & 1);
            short8 pfr[2];
#pragma unroll
            for (int f = 0; f < 2; f++) {
                unsigned int X = P32[f][mt][bse],     Y = P32[f][mt][bse + 1];
                unsigned int Z = P32[f][mt][bse + 2], W = P32[f][mt][bse + 3];
                unsigned int sendA = hi ? X : Z;
                unsigned int sendB = hi ? Y : W;
                unsigned int recvA = (unsigned int)__shfl_xor((int)sendA, 32, 64);
                unsigned int recvB = (unsigned int)__shfl_xor((int)sendB, 32, 64);
                union { unsigned int u[4]; short8 s; } pk;
                pk.u[0] = hi ? recvA : X;
                pk.u[1] = hi ? recvB : Y;
                pk.u[2] = hi ? Z : recvA;
                pk.u[3] = hi ? W : recvB;
                pfr[f] = pk.s;
            }
#pragma unroll
            for (int dm = 0; dm < 2; dm++) {
                short8 vf = *(const short8*)(
                    &Vb[(dm * 32 + l32) * 64 + ((2 * sc + hi) ^ e) * 8]);
                oacc[0][dm] = __builtin_amdgcn_mfma_f32_32x32x16_bf16(
                    vf, pfr[0], oacc[0][dm], 0, 0, 0);
                oacc[1][dm] = __builtin_amdgcn_mfma_f32_32x32x16_bf16(
                    vf, pfr[1], oacc[1][dm], 0, 0, 0);
            }
        }
    }

    // each lane covers half the s-range; partner lane^32 has the other half
#pragma unroll
    for (int f = 0; f < 2; f++)
        l_[f] += __shfl_xor(l_[f], 32, 64);

#pragma unroll
    for (int f = 0; f < 2; f++) {
        const int qg = q0w + f * 32 + l32;
        const float invl = 1.0f / l_[f];
#pragma unroll
        for (int dm = 0; dm < 2; dm++)
#pragma unroll
            for (int g = 0; g < 4; g++) {
                int d0 = dm * 32 + 8 * g + 4 * hi;
                ushort4 pk;
                pk.x = f2bf(oacc[f][dm][4 * g + 0] * invl);
                pk.y = f2bf(oacc[f][dm][4 * g + 1] * invl);
                pk.z = f2bf(oacc[f][dm][4 * g + 2] * invl);
                pk.w = f2bf(oacc[f][dm][4 * g + 3] * invl);
                *(ushort4*)(o + ((size_t)b_ * SEQ + qg) * HID + h_ * HD + d0) = pk;
            }
    }
}

// ---------------------------------------------------------------------------
extern "C" void kernel_launch(void* const* d_in, const int* in_sizes, int n_in,
                              void* d_out, int out_size, void* d_ws, size_t ws_size,
                              hipStream_t stream)
{
    const float* x  = (const float*)d_in[0];
    const float* Wq = (const float*)d_in[1];
    const float* bq = (const float*)d_in[2];
    const float* Wk = (const float*)d_in[3];
    const float* bk = (const float*)d_in[4];
    const float* Wv = (const float*)d_in[5];
    const float* bv = (const float*)d_in[6];
    const float* Wo = (const float*)d_in[7];
    const float* bo = (const float*)d_in[8];
    float* out = (float*)d_out;

    const size_t TE = (size_t)M_TOT * HID;   // 8,388,608
    const size_t WE = (size_t)HID * HID;     // 1,048,576
    ushort* qws = (ushort*)d_ws;   // Q^T [B,H,D,S]
    ushort* kws = qws + TE;        // K   [B,H,S,D]
    ushort* vws = kws + TE;        // V^T [B,H,D,S]
    ushort* xbf = vws + TE;        // x in bf16; reused as attn output
    ushort* aws = xbf;
    ushort* wqb = xbf + TE;
    ushort* wkb = wqb + WE;
    ushort* wvb = wkb + WE;
    ushort* wob = wvb + WE;        // total ws: 75.5 MB

    convert_bf16<<<(X_F4 + 4 * W_F4) / 256, 256, 0, stream>>>(
        x, Wq, Wk, Wv, Wo, xbf, wqb, wkb, wvb, wob);

    dim3 g1(M_TOT / BM, HID / BN, 3);
    gemm_bf<1><<<g1, 256, 0, stream>>>(xbf, wqb, wkb, wvb, bq, bk, bv,
                                       qws, kws, vws, nullptr);

    dim3 g2(SEQ / 128, BATCH * NH, 1);
    attn_flash<<<g2, 128, 0, stream>>>(qws, kws, vws, aws);

    dim3 g3(M_TOT / BM, HID / BN, 1);
    gemm_bf<0><<<g3, 256, 0, stream>>>(aws, wob, wob, wob, bo, bo, bo,
                                       nullptr, nullptr, nullptr, out);
}